// Round 6
// baseline (218.349 us; speedup 1.0000x reference)
//
#include <hip/hip_runtime.h>
#include <hip/hip_bf16.h>
#include <stdint.h>

// Problem constants (DynamicConv1dTBC): T=2048 B=8 C=1024 H=16 K=7 pad_l=6
#define T_DIM 2048
#define B_DIM 8
#define C_DIM 1024
#define H_DIM 16
#define K_DIM 7
#define M_DIM (T_DIM * B_DIM)   // 16384 rows (m = t*B + b)
#define NLOG 144                // H*K (112) + 2H (32) logit columns
#define CW_STRIDE 128           // compact conv-weights row: 112 wk + 16 gates
#define LSM_STRIDE 146          // 146 ≡ 18 mod 32 -> q-group bank windows 2-way (free)

typedef __attribute__((ext_vector_type(8))) short short8;
typedef __attribute__((ext_vector_type(4))) float floatx4;

__device__ __forceinline__ ushort f2bf(float f) {
    __hip_bfloat16 h = __float2bfloat16(f);
    return *(ushort*)&h;
}

// ---------------------------------------------------------------------------
// Kernel W: fp32 -> bf16 downcast of weights: [w_weight;glu_w] -> wb (144x1024)
// and out_w -> Wb (1024x1024).
// ---------------------------------------------------------------------------
#define S_W  ((size_t)112 * C_DIM)
#define S_G  ((size_t)32 * C_DIM)
#define S_O  ((size_t)C_DIM * C_DIM)
#define S_WG (S_W + S_G)
#define S_CVT (S_WG + S_O)                  // 1,196,032 = 4*256*1168

__global__ __launch_bounds__(256) void cvt_w_kernel(
    const float* __restrict__ w_weight, const float* __restrict__ glu_w,
    const float* __restrict__ out_w,
    ushort* __restrict__ wb, ushort* __restrict__ Wb)
{
    size_t gid = ((size_t)blockIdx.x * 256 + threadIdx.x) * 4;
    const float* src; ushort* dst; size_t off;
    if (gid < S_W)            { src = w_weight; dst = wb;       off = gid; }
    else if (gid < S_WG)      { src = glu_w;    dst = wb + S_W; off = gid - S_W; }
    else                      { src = out_w;    dst = Wb;       off = gid - S_WG; }
    float4 v = *(const float4*)(src + off);
    ushort4 o; o.x = f2bf(v.x); o.y = f2bf(v.y); o.z = f2bf(v.z); o.w = f2bf(v.w);
    *(ushort4*)(dst + off) = o;
}

// ---------------------------------------------------------------------------
// Kernel L: logits GEMM (M=16384, N=144, K=1024) + softmax/gate epilogue.
// Round-6 restructure (latency-bound fix): 512 threads, 8 waves.
// Wave w: row-group g = w&3 (16 rows), K-half kh = w>>2 (512 cols).
//  - 2 waves/SIMD (was 1) and serial chain 16 iters (was 32).
//  - NO in-loop barriers: B fragments read DIRECTLY from global wb
//    (288 KB, L2-resident; fragment addr = wb[(j*16+fr)*C + kb + q*8] is
//    exactly the MFMA B layout) -> compiler free to software-pipeline,
//    waves slide independently.
//  - Partial accs reduced via lsm: kh=0 writes, barrier, kh=1 adds.
//  - lsm stride 146 (≡18 mod 32): epilogue q-groups 2-way banked (free).
// ---------------------------------------------------------------------------
__global__ __launch_bounds__(512) void logits_kernel(
    const float* __restrict__ x,       // (M, C) fp32
    const ushort* __restrict__ wb,     // (144, C) bf16
    const float* __restrict__ glu_b,   // (2H,) fp32
    float* __restrict__ cw)            // (M, 128) fp32
{
    __shared__ float lsm[64][LSM_STRIDE];             // 37,376 B

    const int tid = threadIdx.x;
    const int wave = tid >> 6, lane = tid & 63;
    const int g = wave & 3;              // row-group
    const int kh = wave >> 2;            // K-half
    const int fr = lane & 15, q = lane >> 4;
    const int m0 = blockIdx.x * 64;
    const int mrow = m0 + g * 16 + fr;
    const int kb = kh * 512;

    floatx4 acc[9];
#pragma unroll
    for (int j = 0; j < 9; ++j) acc[j] = (floatx4){0.f, 0.f, 0.f, 0.f};

    const float* arow = x + (size_t)mrow * C_DIM + kb + q * 8;
    const ushort* brow = wb + (size_t)fr * C_DIM + kb + q * 8;

    float4 a0 = *(const float4*)(arow);
    float4 a1 = *(const float4*)(arow + 4);

#pragma unroll 2
    for (int kc = 0; kc < 16; ++kc) {
        short8 a;
        a[0] = (short)f2bf(a0.x); a[1] = (short)f2bf(a0.y);
        a[2] = (short)f2bf(a0.z); a[3] = (short)f2bf(a0.w);
        a[4] = (short)f2bf(a1.x); a[5] = (short)f2bf(a1.y);
        a[6] = (short)f2bf(a1.z); a[7] = (short)f2bf(a1.w);
        if (kc < 15) {                        // prefetch next A
            a0 = *(const float4*)(arow + (kc + 1) * 32);
            a1 = *(const float4*)(arow + (kc + 1) * 32 + 4);
        }
#pragma unroll
        for (int j = 0; j < 9; ++j) {
            short8 b = *(const short8*)(brow + (size_t)j * 16 * C_DIM + kc * 32);
            acc[j] = __builtin_amdgcn_mfma_f32_16x16x32_bf16(a, b, acc[j], 0, 0, 0);
        }
    }

    // ---- reduce K-halves through lsm ----
    if (kh == 0) {
#pragma unroll
        for (int j = 0; j < 9; ++j)
#pragma unroll
            for (int r = 0; r < 4; ++r)
                lsm[g * 16 + q * 4 + r][j * 16 + fr] = acc[j][r];
    }
    __syncthreads();
    if (kh == 1) {
#pragma unroll
        for (int j = 0; j < 9; ++j)
#pragma unroll
            for (int r = 0; r < 4; ++r)
                lsm[g * 16 + q * 4 + r][j * 16 + fr] += acc[j][r];
    }
    __syncthreads();

    // ---- softmax + gate -> cw (512 threads: 8/row, 2 heads each) ----
    {
        const int row = tid >> 3;             // [0,64)
        const int hbase = (tid & 7) * 2;      // 2 heads per thread
        float* crow = cw + (size_t)(m0 + row) * CW_STRIDE;
#pragma unroll
        for (int hh = 0; hh < 2; ++hh) {
            const int h = hbase + hh;
            float l[K_DIM];
            float mx = -1e30f;
#pragma unroll
            for (int k = 0; k < K_DIM; ++k) { l[k] = lsm[row][h * K_DIM + k]; mx = fmaxf(mx, l[k]); }
            float s = 0.f;
#pragma unroll
            for (int k = 0; k < K_DIM; ++k) { l[k] = __expf(l[k] - mx); s += l[k]; }
            float inv = 1.f / s;
#pragma unroll
            for (int k = 0; k < K_DIM; ++k) crow[h * K_DIM + k] = l[k] * inv;
            float ga = lsm[row][112 + 2 * h] + glu_b[2 * h];
            float gb = lsm[row][113 + 2 * h] + glu_b[2 * h + 1];
            crow[112 + h] = ga * (1.f / (1.f + __expf(-gb)));
        }
    }
}

// ---------------------------------------------------------------------------
// Kernel V: depthwise dynamic conv + gate. (unchanged)
// ---------------------------------------------------------------------------
__global__ __launch_bounds__(256) void conv_kernel(
    const float* __restrict__ x,        // (M, C) fp32
    const float* __restrict__ cw,       // (M, 128) fp32
    const int* __restrict__ padding_l_, // scalar
    ushort* __restrict__ y)             // (M, C) bf16
{
    const int lb = (blockIdx.x & 7) * 512 + (blockIdx.x >> 3);  // XCD-contig t
    const int wave = threadIdx.x >> 6, lane = threadIdx.x & 63;
    const int m = lb * 4 + wave;
    const int t = m >> 3;
    const int pad = *padding_l_;
    const int h = lane >> 2;

    const float* crow = cw + (size_t)m * CW_STRIDE;
    float wt[K_DIM];
#pragma unroll
    for (int k = 0; k < K_DIM; ++k) wt[k] = crow[h * K_DIM + k];
    const float g = crow[112 + h];

    const int c0 = lane * 16;
    float av[16];
#pragma unroll
    for (int i = 0; i < 16; ++i) av[i] = 0.f;

#pragma unroll
    for (int k = 0; k < K_DIM; ++k) {
        int ts = t + k - pad;
        if (ts < 0 || ts >= T_DIM) continue;
        float wv = wt[k];
        const float4* xp = (const float4*)(x + ((size_t)m + 8 * (k - pad)) * C_DIM + c0);
        float4 u0 = xp[0], u1 = xp[1], u2 = xp[2], u3 = xp[3];
        av[0]  += wv * u0.x; av[1]  += wv * u0.y; av[2]  += wv * u0.z; av[3]  += wv * u0.w;
        av[4]  += wv * u1.x; av[5]  += wv * u1.y; av[6]  += wv * u1.z; av[7]  += wv * u1.w;
        av[8]  += wv * u2.x; av[9]  += wv * u2.y; av[10] += wv * u2.z; av[11] += wv * u2.w;
        av[12] += wv * u3.x; av[13] += wv * u3.y; av[14] += wv * u3.z; av[15] += wv * u3.w;
    }

    uint32_t o[8];
#pragma unroll
    for (int i = 0; i < 8; ++i)
        o[i] = (uint32_t)f2bf(av[2 * i] * g) | ((uint32_t)f2bf(av[2 * i + 1] * g) << 16);
    uint4* yr = (uint4*)(y + (size_t)m * C_DIM + c0);
    yr[0] = (uint4){o[0], o[1], o[2], o[3]};
    yr[1] = (uint4){o[4], o[5], o[6], o[7]};
}

// ---------------------------------------------------------------------------
// Kernel C: out = y @ Wb^T + bias.  256x256 tile, 8 waves, BK=64, 4-phase
// rhythm. (unchanged from round 5 — dropped below logits in the profile)
// ---------------------------------------------------------------------------
__global__ __launch_bounds__(512, 2) void out_gemm(
    const ushort* __restrict__ y,     // (M, C) bf16
    const ushort* __restrict__ Wb,    // (C, C) bf16
    const float* __restrict__ bias,   // (C,) fp32
    float* __restrict__ out)          // (M, C) fp32
{
    // [buf][region: A0,A1,B0,B1][128 rows * 64 cols bf16] = 128 KB
    __shared__ __align__(16) ushort SM[2][4][128 * 64];

    const int orig = (blockIdx.x & 7) * 32 + (blockIdx.x >> 3);
    const int bm = orig >> 2;            // M/256 = 64
    const int bn = orig & 3;             // N/256 = 4
    const int m0 = bm * 256, n0 = bn * 256;
    const int tid = threadIdx.x;
    const int lane = tid & 63, wave = tid >> 6;
    const int wr = wave >> 2;            // M-half owner (A region = wr)
    const int wc = wave & 3;             // N-quarter (B region = wc>>1)
    const int fr = lane & 15, q = lane >> 4;
    // per-thread swizzled granule byte-offsets for the two K=32 slices
    const int g0 = ((q) ^ (fr & 7)) * 8;       // ushort offset, ks=0
    const int g1 = ((4 + q) ^ (fr & 7)) * 8;   // ks=1

    floatx4 acc[8][4];
#pragma unroll
    for (int i = 0; i < 8; ++i)
#pragma unroll
        for (int j = 0; j < 4; ++j) acc[i][j] = (floatx4){0.f, 0.f, 0.f, 0.f};

    // stage one 128x64 region: mat 0=A(y rows m0+), 1=B(Wb rows n0+)
    auto stageH = [&](int buf, int mat, int half, int k0) {
        const ushort* src = mat ? Wb : y;
        const int row0 = (mat ? n0 : m0) + half * 128;
        ushort* dst = &SM[buf][mat * 2 + half][0];
#pragma unroll
        for (int j = 0; j < 2; ++j) {
            int idx = j * 512 + tid;          // 16B granule slot [0,1024)
            int r = idx >> 3, gl = idx & 7;
            int gs = gl ^ (r & 7);            // pre-swizzled global source
            __builtin_amdgcn_global_load_lds(
                (const __attribute__((address_space(1))) void*)(src + (size_t)(row0 + r) * C_DIM + k0 + gs * 8),
                (__attribute__((address_space(3))) void*)(dst + idx * 8), 16, 0, 0);
        }
    };

    // prologue: tile0 complete + B halves of tile1 (6 regions, 12 loads/thr)
    stageH(0, 0, 0, 0);  stageH(0, 0, 1, 0);    // A0_0 A1_0
    stageH(0, 1, 0, 0);  stageH(0, 1, 1, 0);    // B0_0 B1_0
    stageH(1, 1, 0, 64); stageH(1, 1, 1, 64);   // B0_1 B1_1
    asm volatile("s_waitcnt vmcnt(4)" ::: "memory");  // tile0 landed; B_1 in flight
    __builtin_amdgcn_s_barrier();
    asm volatile("" ::: "memory");

    short8 a[4][2], b[4][2];
    for (int t = 0; t < 16; ++t) {
        const int buf = t & 1;
        const ushort* Ar = &SM[buf][wr][0];
        const ushort* Br = &SM[buf][2 + (wc >> 1)][0];
        const int brb = (wc & 1) * 64;

        // ---------------- P1 ----------------
#pragma unroll
        for (int mf = 0; mf < 4; ++mf) {
            int ro = (mf * 16 + fr) * 64;
            a[mf][0] = *(const short8*)(Ar + ro + g0);
            a[mf][1] = *(const short8*)(Ar + ro + g1);
        }
#pragma unroll
        for (int nf = 0; nf < 2; ++nf) {
            int ro = (brb + nf * 16 + fr) * 64;
            b[nf][0] = *(const short8*)(Br + ro + g0);
            b[nf][1] = *(const short8*)(Br + ro + g1);
        }
        if (t + 1 < 16) stageH(buf ^ 1, 0, 0, (t + 1) * 64);
        __builtin_amdgcn_s_barrier();
        asm volatile("s_waitcnt lgkmcnt(0)" ::: "memory");
        __builtin_amdgcn_s_setprio(1);
#pragma unroll
        for (int ks = 0; ks < 2; ++ks)
#pragma unroll
            for (int mf = 0; mf < 4; ++mf)
#pragma unroll
                for (int nf = 0; nf < 2; ++nf)
                    acc[mf][nf] = __builtin_amdgcn_mfma_f32_16x16x32_bf16(a[mf][ks], b[nf][ks], acc[mf][nf], 0, 0, 0);
        __builtin_amdgcn_s_setprio(0);
        asm volatile("" ::: "memory");
        __builtin_amdgcn_s_barrier();
        asm volatile("" ::: "memory");

        // ---------------- P2 ----------------
#pragma unroll
        for (int nf = 2; nf < 4; ++nf) {
            int ro = (brb + nf * 16 + fr) * 64;
            b[nf][0] = *(const short8*)(Br + ro + g0);
            b[nf][1] = *(const short8*)(Br + ro + g1);
        }
        if (t + 1 < 16) stageH(buf ^ 1, 0, 1, (t + 1) * 64);
        __builtin_amdgcn_s_barrier();
        asm volatile("s_waitcnt lgkmcnt(0)" ::: "memory");
        __builtin_amdgcn_s_setprio(1);
#pragma unroll
        for (int ks = 0; ks < 2; ++ks)
#pragma unroll
            for (int mf = 0; mf < 4; ++mf)
#pragma unroll
                for (int nf = 2; nf < 4; ++nf)
                    acc[mf][nf] = __builtin_amdgcn_mfma_f32_16x16x32_bf16(a[mf][ks], b[nf][ks], acc[mf][nf], 0, 0, 0);
        __builtin_amdgcn_s_setprio(0);
        asm volatile("" ::: "memory");
        __builtin_amdgcn_s_barrier();
        asm volatile("" ::: "memory");

        // ---------------- P3 ----------------
#pragma unroll
        for (int mf = 0; mf < 4; ++mf) {
            int ro = ((mf + 4) * 16 + fr) * 64;
            a[mf][0] = *(const short8*)(Ar + ro + g0);
            a[mf][1] = *(const short8*)(Ar + ro + g1);
        }
        if (t + 2 < 16) stageH(buf, 1, 0, (t + 2) * 64);
        __builtin_amdgcn_s_barrier();
        asm volatile("s_waitcnt lgkmcnt(0)" ::: "memory");
        __builtin_amdgcn_s_setprio(1);
#pragma unroll
        for (int ks = 0; ks < 2; ++ks)
#pragma unroll
            for (int mf = 0; mf < 4; ++mf)
#pragma unroll
                for (int nf = 0; nf < 2; ++nf)
                    acc[mf + 4][nf] = __builtin_amdgcn_mfma_f32_16x16x32_bf16(a[mf][ks], b[nf][ks], acc[mf + 4][nf], 0, 0, 0);
        __builtin_amdgcn_s_setprio(0);
        asm volatile("" ::: "memory");
        __builtin_amdgcn_s_barrier();
        asm volatile("" ::: "memory");

        // ---------------- P4 ----------------
        if (t + 2 < 16) stageH(buf, 1, 1, (t + 2) * 64);
        if (t < 14)       { asm volatile("s_waitcnt vmcnt(4)" ::: "memory"); }
        else if (t == 14) { asm volatile("s_waitcnt vmcnt(0)" ::: "memory"); }
        __builtin_amdgcn_s_barrier();
        asm volatile("" ::: "memory");
        __builtin_amdgcn_s_setprio(1);
#pragma unroll
        for (int ks = 0; ks < 2; ++ks)
#pragma unroll
            for (int mf = 0; mf < 4; ++mf)
#pragma unroll
                for (int nf = 2; nf < 4; ++nf)
                    acc[mf + 4][nf] = __builtin_amdgcn_mfma_f32_16x16x32_bf16(a[mf][ks], b[nf][ks], acc[mf + 4][nf], 0, 0, 0);
        __builtin_amdgcn_s_setprio(0);
        asm volatile("" ::: "memory");
        __builtin_amdgcn_s_barrier();
        asm volatile("" ::: "memory");
    }

    // ---- epilogue: direct stores (wave tile 128x64) ----
#pragma unroll
    for (int nf = 0; nf < 4; ++nf) {
        int n = n0 + wc * 64 + nf * 16 + fr;
        float bv = bias[n];
#pragma unroll
        for (int mf = 0; mf < 8; ++mf) {
#pragma unroll
            for (int r = 0; r < 4; ++r) {
                int m = m0 + wr * 128 + mf * 16 + q * 4 + r;
                out[(size_t)m * C_DIM + n] = acc[mf][nf][r] + bv;
            }
        }
    }
}

// ---------------------------------------------------------------------------
extern "C" void kernel_launch(void* const* d_in, const int* in_sizes, int n_in,
                              void* d_out, int out_size, void* d_ws, size_t ws_size,
                              hipStream_t stream) {
    const float* x        = (const float*)d_in[0];
    const float* w_weight = (const float*)d_in[1];
    const float* glu_w    = (const float*)d_in[2];
    const float* glu_b    = (const float*)d_in[3];
    const float* out_w    = (const float*)d_in[4];
    const float* out_b    = (const float*)d_in[5];
    const int* padding_l  = (const int*)d_in[6];
    float* out = (float*)d_out;

    char* ws = (char*)d_ws;
    ushort* y  = (ushort*)ws;                          // M*C bf16   (33.5 MB)
    ushort* wb = y + (size_t)M_DIM * C_DIM;            // 144*C bf16 (0.3 MB)
    ushort* Wb = wb + S_WG;                            // C*C bf16   (2.1 MB)
    float* cwp = (float*)(Wb + S_O);                   // M*128 fp32 (8.4 MB)

    cvt_w_kernel<<<S_CVT / 4 / 256, 256, 0, stream>>>(w_weight, glu_w, out_w, wb, Wb);
    logits_kernel<<<M_DIM / 64, 512, 0, stream>>>(x, wb, glu_b, cwp);
    conv_kernel<<<M_DIM / 4, 256, 0, stream>>>(x, cwp, padding_l, y);
    out_gemm<<<(M_DIM / 256) * (C_DIM / 256), 512, 0, stream>>>(y, Wb, out_b, out);
}

// Round 7
// 210.563 us; speedup vs baseline: 1.0370x; 1.0370x over previous
//
#include <hip/hip_runtime.h>
#include <hip/hip_bf16.h>
#include <stdint.h>

// Problem constants (DynamicConv1dTBC): T=2048 B=8 C=1024 H=16 K=7 pad_l=6
#define T_DIM 2048
#define B_DIM 8
#define C_DIM 1024
#define H_DIM 16
#define K_DIM 7
#define M_DIM (T_DIM * B_DIM)   // 16384 rows (m = t*B + b)
#define NLOG 144                // H*K (112) + 2H (32) logit columns
#define LSM_STRIDE 146          // 146 ≡ 18 mod 32 -> q-group bank windows 2-way (free)

typedef __attribute__((ext_vector_type(8))) short short8;
typedef __attribute__((ext_vector_type(4))) float floatx4;

__device__ __forceinline__ ushort f2bf(float f) {
    __hip_bfloat16 h = __float2bfloat16(f);
    return *(ushort*)&h;
}

// ---------------------------------------------------------------------------
// Kernel W: fp32 -> bf16 downcast of weights: [w_weight;glu_w] -> wb (144x1024)
// and out_w -> Wb (1024x1024).
// ---------------------------------------------------------------------------
#define S_W  ((size_t)112 * C_DIM)
#define S_G  ((size_t)32 * C_DIM)
#define S_O  ((size_t)C_DIM * C_DIM)
#define S_WG (S_W + S_G)
#define S_CVT (S_WG + S_O)                  // 1,196,032 = 4*256*1168

__global__ __launch_bounds__(256) void cvt_w_kernel(
    const float* __restrict__ w_weight, const float* __restrict__ glu_w,
    const float* __restrict__ out_w,
    ushort* __restrict__ wb, ushort* __restrict__ Wb)
{
    size_t gid = ((size_t)blockIdx.x * 256 + threadIdx.x) * 4;
    const float* src; ushort* dst; size_t off;
    if (gid < S_W)            { src = w_weight; dst = wb;       off = gid; }
    else if (gid < S_WG)      { src = glu_w;    dst = wb + S_W; off = gid - S_W; }
    else                      { src = out_w;    dst = Wb;       off = gid - S_WG; }
    float4 v = *(const float4*)(src + off);
    ushort4 o; o.x = f2bf(v.x); o.y = f2bf(v.y); o.z = f2bf(v.z); o.w = f2bf(v.w);
    *(ushort4*)(dst + off) = o;
}

// ---------------------------------------------------------------------------
// Kernel LC: FUSED logits GEMM + softmax/gate + depthwise conv -> y (bf16).
// Rationale (r7): logits' 49 us is invariant to occupancy/barriers/B-path/
// memory-tier (r3-r6) -> stop shaving it, amortize it. conv consumes cw
// row-for-row with ZERO halo on cw (weights at t only; only x is read at
// t-6..t), so per-64-row-block fusion is exact: softmax stays in LDS,
// conv reads weights from LDS + x from global, writes y. Deletes the
// 16.8 MB cw round-trip and one dispatch.
// Phase 1 (GEMM) is byte-identical to round 6 for attribution.
// Gates go to a separate gat[] buffer: in-place gate writes would clobber
// raw gb logits read by the neighboring head's thread (race).
// XCD-chunked swizzle: consecutive t-ranges per XCD -> conv halo L2-local.
// ---------------------------------------------------------------------------
__global__ __launch_bounds__(512) void logits_conv_kernel(
    const float* __restrict__ x,        // (M, C) fp32
    const ushort* __restrict__ wb,      // (144, C) bf16
    const float* __restrict__ glu_b,    // (2H,) fp32
    const int* __restrict__ padding_l_, // scalar
    ushort* __restrict__ y)             // (M, C) bf16
{
    __shared__ float lsm[64][LSM_STRIDE];             // 37,376 B
    __shared__ float gat[64][H_DIM];                  //  4,096 B

    const int tid = threadIdx.x;
    const int wave = tid >> 6, lane = tid & 63;
    const int g = wave & 3;              // row-group
    const int kh = wave >> 2;            // K-half
    const int fr = lane & 15, q = lane >> 4;
    // XCD-chunk swizzle (256 = 8*32, bijective): XCD k owns contiguous m0
    const int orig = (blockIdx.x & 7) * 32 + (blockIdx.x >> 3);
    const int m0 = orig * 64;
    const int mrow = m0 + g * 16 + fr;
    const int kb = kh * 512;

    floatx4 acc[9];
#pragma unroll
    for (int j = 0; j < 9; ++j) acc[j] = (floatx4){0.f, 0.f, 0.f, 0.f};

    const float* arow = x + (size_t)mrow * C_DIM + kb + q * 8;
    const ushort* brow = wb + (size_t)fr * C_DIM + kb + q * 8;

    float4 a0 = *(const float4*)(arow);
    float4 a1 = *(const float4*)(arow + 4);

#pragma unroll 2
    for (int kc = 0; kc < 16; ++kc) {
        short8 a;
        a[0] = (short)f2bf(a0.x); a[1] = (short)f2bf(a0.y);
        a[2] = (short)f2bf(a0.z); a[3] = (short)f2bf(a0.w);
        a[4] = (short)f2bf(a1.x); a[5] = (short)f2bf(a1.y);
        a[6] = (short)f2bf(a1.z); a[7] = (short)f2bf(a1.w);
        if (kc < 15) {                        // prefetch next A
            a0 = *(const float4*)(arow + (kc + 1) * 32);
            a1 = *(const float4*)(arow + (kc + 1) * 32 + 4);
        }
#pragma unroll
        for (int j = 0; j < 9; ++j) {
            short8 b = *(const short8*)(brow + (size_t)j * 16 * C_DIM + kc * 32);
            acc[j] = __builtin_amdgcn_mfma_f32_16x16x32_bf16(a, b, acc[j], 0, 0, 0);
        }
    }

    // ---- phase 2: reduce K-halves through lsm ----
    if (kh == 0) {
#pragma unroll
        for (int j = 0; j < 9; ++j)
#pragma unroll
            for (int r = 0; r < 4; ++r)
                lsm[g * 16 + q * 4 + r][j * 16 + fr] = acc[j][r];
    }
    __syncthreads();
    if (kh == 1) {
#pragma unroll
        for (int j = 0; j < 9; ++j)
#pragma unroll
            for (int r = 0; r < 4; ++r)
                lsm[g * 16 + q * 4 + r][j * 16 + fr] += acc[j][r];
    }
    __syncthreads();

    // ---- phase 3: softmax (in-place, cols 0..111) + gate -> gat ----
    {
        const int row = tid >> 3;             // [0,64)
        const int hbase = (tid & 7) * 2;      // 2 heads per thread
#pragma unroll
        for (int hh = 0; hh < 2; ++hh) {
            const int h = hbase + hh;
            float l[K_DIM];
            float mx = -1e30f;
#pragma unroll
            for (int k = 0; k < K_DIM; ++k) { l[k] = lsm[row][h * K_DIM + k]; mx = fmaxf(mx, l[k]); }
            float s = 0.f;
#pragma unroll
            for (int k = 0; k < K_DIM; ++k) { l[k] = __expf(l[k] - mx); s += l[k]; }
            float inv = 1.f / s;
#pragma unroll
            for (int k = 0; k < K_DIM; ++k) lsm[row][h * K_DIM + k] = l[k] * inv;
            float ga = lsm[row][112 + 2 * h] + glu_b[2 * h];
            float gb = lsm[row][113 + 2 * h] + glu_b[2 * h + 1];
            gat[row][h] = ga * (1.f / (1.f + __expf(-gb)));
        }
    }
    __syncthreads();

    // ---- phase 4: depthwise conv + gate -> y (conv_kernel body per row) ----
    {
        const int pad = *padding_l_;
        const int h = lane >> 2;
        const int c0 = lane * 16;
#pragma unroll
        for (int rr = 0; rr < 8; ++rr) {
            const int r = wave * 8 + rr;
            const int m = m0 + r;
            const int t = m >> 3;

            float wt[K_DIM];
#pragma unroll
            for (int k = 0; k < K_DIM; ++k) wt[k] = lsm[r][h * K_DIM + k];
            const float gv = gat[r][h];

            float av[16];
#pragma unroll
            for (int i = 0; i < 16; ++i) av[i] = 0.f;

#pragma unroll
            for (int k = 0; k < K_DIM; ++k) {
                int ts = t + k - pad;
                if (ts < 0 || ts >= T_DIM) continue;
                float wv = wt[k];
                const float4* xp = (const float4*)(x + ((size_t)m + 8 * (k - pad)) * C_DIM + c0);
                float4 u0 = xp[0], u1 = xp[1], u2 = xp[2], u3 = xp[3];
                av[0]  += wv * u0.x; av[1]  += wv * u0.y; av[2]  += wv * u0.z; av[3]  += wv * u0.w;
                av[4]  += wv * u1.x; av[5]  += wv * u1.y; av[6]  += wv * u1.z; av[7]  += wv * u1.w;
                av[8]  += wv * u2.x; av[9]  += wv * u2.y; av[10] += wv * u2.z; av[11] += wv * u2.w;
                av[12] += wv * u3.x; av[13] += wv * u3.y; av[14] += wv * u3.z; av[15] += wv * u3.w;
            }

            uint32_t o[8];
#pragma unroll
            for (int i = 0; i < 8; ++i)
                o[i] = (uint32_t)f2bf(av[2 * i] * gv) | ((uint32_t)f2bf(av[2 * i + 1] * gv) << 16);
            uint4* yr = (uint4*)(y + (size_t)m * C_DIM + c0);
            yr[0] = (uint4){o[0], o[1], o[2], o[3]};
            yr[1] = (uint4){o[4], o[5], o[6], o[7]};
        }
    }
}

// ---------------------------------------------------------------------------
// Kernel C: out = y @ Wb^T + bias.  256x256 tile, 8 waves, BK=64, 4-phase
// rhythm. (unchanged from round 5)
// ---------------------------------------------------------------------------
__global__ __launch_bounds__(512, 2) void out_gemm(
    const ushort* __restrict__ y,     // (M, C) bf16
    const ushort* __restrict__ Wb,    // (C, C) bf16
    const float* __restrict__ bias,   // (C,) fp32
    float* __restrict__ out)          // (M, C) fp32
{
    // [buf][region: A0,A1,B0,B1][128 rows * 64 cols bf16] = 128 KB
    __shared__ __align__(16) ushort SM[2][4][128 * 64];

    const int orig = (blockIdx.x & 7) * 32 + (blockIdx.x >> 3);
    const int bm = orig >> 2;            // M/256 = 64
    const int bn = orig & 3;             // N/256 = 4
    const int m0 = bm * 256, n0 = bn * 256;
    const int tid = threadIdx.x;
    const int lane = tid & 63, wave = tid >> 6;
    const int wr = wave >> 2;            // M-half owner (A region = wr)
    const int wc = wave & 3;             // N-quarter (B region = wc>>1)
    const int fr = lane & 15, q = lane >> 4;
    // per-thread swizzled granule byte-offsets for the two K=32 slices
    const int g0 = ((q) ^ (fr & 7)) * 8;       // ushort offset, ks=0
    const int g1 = ((4 + q) ^ (fr & 7)) * 8;   // ks=1

    floatx4 acc[8][4];
#pragma unroll
    for (int i = 0; i < 8; ++i)
#pragma unroll
        for (int j = 0; j < 4; ++j) acc[i][j] = (floatx4){0.f, 0.f, 0.f, 0.f};

    // stage one 128x64 region: mat 0=A(y rows m0+), 1=B(Wb rows n0+)
    auto stageH = [&](int buf, int mat, int half, int k0) {
        const ushort* src = mat ? Wb : y;
        const int row0 = (mat ? n0 : m0) + half * 128;
        ushort* dst = &SM[buf][mat * 2 + half][0];
#pragma unroll
        for (int j = 0; j < 2; ++j) {
            int idx = j * 512 + tid;          // 16B granule slot [0,1024)
            int r = idx >> 3, gl = idx & 7;
            int gs = gl ^ (r & 7);            // pre-swizzled global source
            __builtin_amdgcn_global_load_lds(
                (const __attribute__((address_space(1))) void*)(src + (size_t)(row0 + r) * C_DIM + k0 + gs * 8),
                (__attribute__((address_space(3))) void*)(dst + idx * 8), 16, 0, 0);
        }
    };

    // prologue: tile0 complete + B halves of tile1 (6 regions, 12 loads/thr)
    stageH(0, 0, 0, 0);  stageH(0, 0, 1, 0);    // A0_0 A1_0
    stageH(0, 1, 0, 0);  stageH(0, 1, 1, 0);    // B0_0 B1_0
    stageH(1, 1, 0, 64); stageH(1, 1, 1, 64);   // B0_1 B1_1
    asm volatile("s_waitcnt vmcnt(4)" ::: "memory");  // tile0 landed; B_1 in flight
    __builtin_amdgcn_s_barrier();
    asm volatile("" ::: "memory");

    short8 a[4][2], b[4][2];
    for (int t = 0; t < 16; ++t) {
        const int buf = t & 1;
        const ushort* Ar = &SM[buf][wr][0];
        const ushort* Br = &SM[buf][2 + (wc >> 1)][0];
        const int brb = (wc & 1) * 64;

        // ---------------- P1 ----------------
#pragma unroll
        for (int mf = 0; mf < 4; ++mf) {
            int ro = (mf * 16 + fr) * 64;
            a[mf][0] = *(const short8*)(Ar + ro + g0);
            a[mf][1] = *(const short8*)(Ar + ro + g1);
        }
#pragma unroll
        for (int nf = 0; nf < 2; ++nf) {
            int ro = (brb + nf * 16 + fr) * 64;
            b[nf][0] = *(const short8*)(Br + ro + g0);
            b[nf][1] = *(const short8*)(Br + ro + g1);
        }
        if (t + 1 < 16) stageH(buf ^ 1, 0, 0, (t + 1) * 64);
        __builtin_amdgcn_s_barrier();
        asm volatile("s_waitcnt lgkmcnt(0)" ::: "memory");
        __builtin_amdgcn_s_setprio(1);
#pragma unroll
        for (int ks = 0; ks < 2; ++ks)
#pragma unroll
            for (int mf = 0; mf < 4; ++mf)
#pragma unroll
                for (int nf = 0; nf < 2; ++nf)
                    acc[mf][nf] = __builtin_amdgcn_mfma_f32_16x16x32_bf16(a[mf][ks], b[nf][ks], acc[mf][nf], 0, 0, 0);
        __builtin_amdgcn_s_setprio(0);
        asm volatile("" ::: "memory");
        __builtin_amdgcn_s_barrier();
        asm volatile("" ::: "memory");

        // ---------------- P2 ----------------
#pragma unroll
        for (int nf = 2; nf < 4; ++nf) {
            int ro = (brb + nf * 16 + fr) * 64;
            b[nf][0] = *(const short8*)(Br + ro + g0);
            b[nf][1] = *(const short8*)(Br + ro + g1);
        }
        if (t + 1 < 16) stageH(buf ^ 1, 0, 1, (t + 1) * 64);
        __builtin_amdgcn_s_barrier();
        asm volatile("s_waitcnt lgkmcnt(0)" ::: "memory");
        __builtin_amdgcn_s_setprio(1);
#pragma unroll
        for (int ks = 0; ks < 2; ++ks)
#pragma unroll
            for (int mf = 0; mf < 4; ++mf)
#pragma unroll
                for (int nf = 2; nf < 4; ++nf)
                    acc[mf][nf] = __builtin_amdgcn_mfma_f32_16x16x32_bf16(a[mf][ks], b[nf][ks], acc[mf][nf], 0, 0, 0);
        __builtin_amdgcn_s_setprio(0);
        asm volatile("" ::: "memory");
        __builtin_amdgcn_s_barrier();
        asm volatile("" ::: "memory");

        // ---------------- P3 ----------------
#pragma unroll
        for (int mf = 0; mf < 4; ++mf) {
            int ro = ((mf + 4) * 16 + fr) * 64;
            a[mf][0] = *(const short8*)(Ar + ro + g0);
            a[mf][1] = *(const short8*)(Ar + ro + g1);
        }
        if (t + 2 < 16) stageH(buf, 1, 0, (t + 2) * 64);
        __builtin_amdgcn_s_barrier();
        asm volatile("s_waitcnt lgkmcnt(0)" ::: "memory");
        __builtin_amdgcn_s_setprio(1);
#pragma unroll
        for (int ks = 0; ks < 2; ++ks)
#pragma unroll
            for (int mf = 0; mf < 4; ++mf)
#pragma unroll
                for (int nf = 0; nf < 2; ++nf)
                    acc[mf + 4][nf] = __builtin_amdgcn_mfma_f32_16x16x32_bf16(a[mf][ks], b[nf][ks], acc[mf + 4][nf], 0, 0, 0);
        __builtin_amdgcn_s_setprio(0);
        asm volatile("" ::: "memory");
        __builtin_amdgcn_s_barrier();
        asm volatile("" ::: "memory");

        // ---------------- P4 ----------------
        if (t + 2 < 16) stageH(buf, 1, 1, (t + 2) * 64);
        if (t < 14)       { asm volatile("s_waitcnt vmcnt(4)" ::: "memory"); }
        else if (t == 14) { asm volatile("s_waitcnt vmcnt(0)" ::: "memory"); }
        __builtin_amdgcn_s_barrier();
        asm volatile("" ::: "memory");
        __builtin_amdgcn_s_setprio(1);
#pragma unroll
        for (int ks = 0; ks < 2; ++ks)
#pragma unroll
            for (int mf = 0; mf < 4; ++mf)
#pragma unroll
                for (int nf = 2; nf < 4; ++nf)
                    acc[mf + 4][nf] = __builtin_amdgcn_mfma_f32_16x16x32_bf16(a[mf][ks], b[nf][ks], acc[mf + 4][nf], 0, 0, 0);
        __builtin_amdgcn_s_setprio(0);
        asm volatile("" ::: "memory");
        __builtin_amdgcn_s_barrier();
        asm volatile("" ::: "memory");
    }

    // ---- epilogue: direct stores (wave tile 128x64) ----
#pragma unroll
    for (int nf = 0; nf < 4; ++nf) {
        int n = n0 + wc * 64 + nf * 16 + fr;
        float bv = bias[n];
#pragma unroll
        for (int mf = 0; mf < 8; ++mf) {
#pragma unroll
            for (int r = 0; r < 4; ++r) {
                int m = m0 + wr * 128 + mf * 16 + q * 4 + r;
                out[(size_t)m * C_DIM + n] = acc[mf][nf][r] + bv;
            }
        }
    }
}

// ---------------------------------------------------------------------------
extern "C" void kernel_launch(void* const* d_in, const int* in_sizes, int n_in,
                              void* d_out, int out_size, void* d_ws, size_t ws_size,
                              hipStream_t stream) {
    const float* x        = (const float*)d_in[0];
    const float* w_weight = (const float*)d_in[1];
    const float* glu_w    = (const float*)d_in[2];
    const float* glu_b    = (const float*)d_in[3];
    const float* out_w    = (const float*)d_in[4];
    const float* out_b    = (const float*)d_in[5];
    const int* padding_l  = (const int*)d_in[6];
    float* out = (float*)d_out;

    char* ws = (char*)d_ws;
    ushort* y  = (ushort*)ws;                          // M*C bf16   (33.5 MB)
    ushort* wb = y + (size_t)M_DIM * C_DIM;            // 144*C bf16 (0.3 MB)
    ushort* Wb = wb + S_WG;                            // C*C bf16   (2.1 MB)

    cvt_w_kernel<<<S_CVT / 4 / 256, 256, 0, stream>>>(w_weight, glu_w, out_w, wb, Wb);
    logits_conv_kernel<<<M_DIM / 64, 512, 0, stream>>>(x, wb, glu_b, padding_l, y);
    out_gemm<<<(M_DIM / 256) * (C_DIM / 256), 512, 0, stream>>>(y, Wb, out_b, out);
}